// Round 3
// baseline (18942.082 us; speedup 1.0000x reference)
//
#include <hip/hip_runtime.h>
#include <math.h>

// Problem constants (fixed by reference: x (9,256,32,32) fp32, att (9,32,32) fp32)
#define MR 1024      // m = 32*32 query locations
#define NC 8192      // n = 8*32*32 target locations
#define NCH 256      // channels
#define OT_ITERS 1000
#define IMG_STRIDE 262144  // 256*1024 floats per image
#define PBLK 512           // persistent grid: 2 blocks/CU (256-thread blocks)

__device__ inline float wredMax(float v){
#pragma unroll
  for (int m = 32; m >= 1; m >>= 1) v = fmaxf(v, __shfl_xor(v, m, 64));
  return v;
}
__device__ inline float wredMin(float v){
#pragma unroll
  for (int m = 32; m >= 1; m >>= 1) v = fminf(v, __shfl_xor(v, m, 64));
  return v;
}
__device__ inline float wredSum(float v){
#pragma unroll
  for (int m = 32; m >= 1; m >>= 1) v += __shfl_xor(v, m, 64);
  return v;
}

// monotone float<->uint key (for atomicMin/Max over floats incl. negatives)
__device__ inline unsigned fkey(float f){
  unsigned b = __float_as_uint(f);
  return (b & 0x80000000u) ? ~b : (b | 0x80000000u);
}
__device__ inline float funkey(unsigned k){
  return (k & 0x80000000u) ? __uint_as_float(k & 0x7fffffffu) : __uint_as_float(~k);
}

// tagged dual values: low 32 bits = fp32 value, high 32 bits = epoch.
// 8B relaxed agent-scope atomics -> value+epoch move as one atom; the epoch IS
// the synchronization (no barriers, no fences, no separate publish step).
__device__ inline unsigned long long aload64(const unsigned long long* p){
  return __hip_atomic_load(p, __ATOMIC_RELAXED, __HIP_MEMORY_SCOPE_AGENT);
}
__device__ inline void astore64(unsigned long long* p, unsigned long long x){
  __hip_atomic_store(p, x, __ATOMIC_RELAXED, __HIP_MEMORY_SCOPE_AGENT);
}
__device__ inline unsigned long long packVE(float val, int ep){
  return (unsigned long long)__float_as_uint(val) |
         ((unsigned long long)(unsigned)ep << 32);
}

// K1: squared norms, log marginals, zero-init tagged u/v (epoch 0), acc, minmax keys
__global__ __launch_bounds__(256) void kPrep(const float* __restrict__ x,
                                             const float* __restrict__ att,
                                             float* __restrict__ qq, float* __restrict__ tt,
                                             float* __restrict__ logmu, float* __restrict__ lognu,
                                             unsigned long long* __restrict__ u2t,
                                             unsigned long long* __restrict__ v2t,
                                             float* __restrict__ acc, unsigned* __restrict__ prmI){
  int idx = blockIdx.x * 256 + threadIdx.x;
  if (idx < 9216){
    int img = idx >> 10, pos = idx & 1023;
    const float* p = x + img * IMG_STRIDE + pos;
    float s = 0.f;
#pragma unroll 8
    for (int c = 0; c < NCH; ++c){ float a = p[c * 1024]; s += a * a; }
    float lg = logf(att[idx]);
    if (img == 0){ qq[idx] = s;        logmu[idx] = lg; }
    else         { tt[idx - 1024] = s; lognu[idx - 1024] = lg; }
  }
  if (idx < MR) u2t[idx] = 0ull;   // value 0.0f, epoch 0
  if (idx < NC) v2t[idx] = 0ull;   // value 0.0f, epoch 0
  if (idx == 0){ *acc = 0.f; prmI[0] = 0xFFFFFFFFu; prmI[1] = 0u; }
}

// K2: M[i][j] = qq[i] + tt[j] - 2 * Q_i . T_j ; also global min/max via key atomics
__global__ __launch_bounds__(256) void kGemmM(const float* __restrict__ x,
                                              const float* __restrict__ qq,
                                              const float* __restrict__ tt,
                                              float* __restrict__ M,
                                              unsigned* __restrict__ prmI){
  __shared__ float As[16][68];
  __shared__ float Bs[16][68];
  __shared__ float smn[4], smx[4];
  int jb = blockIdx.x;
  int ib = blockIdx.y;
  int i0 = ib * 64;
  int j0 = jb * 64;
  int k  = j0 >> 10, p0 = j0 & 1023;
  const float* A = x + i0;
  const float* B = x + (1 + k) * IMG_STRIDE + p0;
  int tid = threadIdx.x;
  int lr = tid >> 4, lc = (tid & 15) * 4;
  int ty = tid >> 4, tx = tid & 15;
  float accv[4][4] = {};
  for (int kt = 0; kt < 16; ++kt){
    int c = kt * 16 + lr;
    float4 av = *(const float4*)(A + c * 1024 + lc);
    float4 bv = *(const float4*)(B + c * 1024 + lc);
    *(float4*)(&As[lr][lc]) = av;
    *(float4*)(&Bs[lr][lc]) = bv;
    __syncthreads();
#pragma unroll
    for (int kk = 0; kk < 16; ++kk){
      float4 a = *(const float4*)(&As[kk][ty * 4]);
      float4 b = *(const float4*)(&Bs[kk][tx * 4]);
      float ar[4] = {a.x, a.y, a.z, a.w};
      float br[4] = {b.x, b.y, b.z, b.w};
#pragma unroll
      for (int r = 0; r < 4; ++r)
#pragma unroll
        for (int cc = 0; cc < 4; ++cc) accv[r][cc] += ar[r] * br[cc];
    }
    __syncthreads();
  }
  float tmn = INFINITY, tmx = -INFINITY;
#pragma unroll
  for (int r = 0; r < 4; ++r){
    int i = i0 + ty * 4 + r;
    float qi = qq[i];
    float o[4];
#pragma unroll
    for (int cc = 0; cc < 4; ++cc){
      o[cc] = qi + tt[j0 + tx * 4 + cc] - 2.f * accv[r][cc];
      tmn = fminf(tmn, o[cc]); tmx = fmaxf(tmx, o[cc]);
    }
    float4 ov = { o[0], o[1], o[2], o[3] };
    *(float4*)(M + (long)i * NC + j0 + tx * 4) = ov;
  }
  int lane = tid & 63, w = tid >> 6;
  tmn = wredMin(tmn); tmx = wredMax(tmx);
  if (lane == 0){ smn[w] = tmn; smx[w] = tmx; }
  __syncthreads();
  if (tid == 0){
    float bmn = fminf(fminf(smn[0], smn[1]), fminf(smn[2], smn[3]));
    float bmx = fmaxf(fmaxf(smx[0], smx[1]), fmaxf(smx[2], smx[3]));
    atomicMin(&prmI[0], fkey(bmn));
    atomicMax(&prmI[1], fkey(bmx));
  }
}

// K2b: one pass over M -> Mq (u16 row-major) + Mtq (u16 transposed); writes prm scale
__global__ __launch_bounds__(256) void kQuantTrans(const float* __restrict__ M,
                                                   unsigned short* __restrict__ Mq,
                                                   unsigned short* __restrict__ Mtq,
                                                   float* __restrict__ prm){
  __shared__ float tile[64][65];
  const unsigned* prmI = (const unsigned*)prm;
  float mn = funkey(prmI[0]);
  float mx = funkey(prmI[1]);
  float rng = mx - mn;
  float inv = (rng > 0.f) ? 65535.0f / rng : 0.f;
  float sc  = (rng > 0.f) ? rng / 65535.0f : 0.f;
  int i0 = blockIdx.y * 64;
  int j0 = blockIdx.x * 64;
  int t = threadIdx.x;
  int tc = t & 63, tr = t >> 6;
#pragma unroll
  for (int rr = 0; rr < 64; rr += 4)
    tile[rr + tr][tc] = M[(long)(i0 + rr + tr) * NC + j0 + tc];
  __syncthreads();
#pragma unroll
  for (int rr = 0; rr < 64; rr += 4){
    float a = tile[rr + tr][tc];
    int qa = (int)lrintf((a - mn) * inv);
    qa = qa < 0 ? 0 : (qa > 65535 ? 65535 : qa);
    Mq[(long)(i0 + rr + tr) * NC + j0 + tc] = (unsigned short)qa;
    float b = tile[tc][rr + tr];
    int qb = (int)lrintf((b - mn) * inv);
    qb = qb < 0 ? 0 : (qb > 65535 ? 65535 : qb);
    Mtq[(long)(j0 + rr + tr) * MR + i0 + tc] = (unsigned short)qb;
  }
  if (blockIdx.x == 0 && blockIdx.y == 0 && t == 0){ prm[2] = mn; prm[3] = sc; }
}

// dequant helpers
#define DQV8(t, base, q4, v0, v1) \
  t[(base)+0] = fmaf(s, (float)((q4).x & 0xFFFFu), (v0).x); \
  t[(base)+1] = fmaf(s, (float)((q4).x >> 16),     (v0).y); \
  t[(base)+2] = fmaf(s, (float)((q4).y & 0xFFFFu), (v0).z); \
  t[(base)+3] = fmaf(s, (float)((q4).y >> 16),     (v0).w); \
  t[(base)+4] = fmaf(s, (float)((q4).z & 0xFFFFu), (v1).x); \
  t[(base)+5] = fmaf(s, (float)((q4).z >> 16),     (v1).y); \
  t[(base)+6] = fmaf(s, (float)((q4).w & 0xFFFFu), (v1).z); \
  t[(base)+7] = fmaf(s, (float)((q4).w >> 16),     (v1).w);

// persistent Sinkhorn, barrier-free dataflow version. Round-0's proven geometry
// (512 blocks x 256 threads, 2 blocks/CU; 2 u-rows + 16 v-cols per block;
// coalesced LDS staging; identical math). Grid barriers replaced by epoch tags
// carried WITH the data in 8B atoms:
//   v epoch after v-pass of iter it = it+1 (initial 0); u epoch after u-pass = it+1.
//   u-pass@it polls v epochs == it;  v-pass@it polls u epochs == it+1.
// A polled atom can never be "too new": v[j]@it+1 requires ALL u@it+1, which
// requires every block to have already consumed v@it. Monotone epochs -> no
// deadlock; blocks self-throttle to <=1 iteration of skew. Mq/Mtq immutable ->
// normal loads, L2-resident.
__global__ __launch_bounds__(256, 2) void kSink4(const unsigned short* __restrict__ Mq,
                                                 const unsigned short* __restrict__ Mtq,
                                                 const float* __restrict__ logmu,
                                                 const float* __restrict__ lognu,
                                                 unsigned long long* __restrict__ u2t,
                                                 unsigned long long* __restrict__ v2t,
                                                 const float* __restrict__ prm){
  __shared__ float sh[8192];
  __shared__ float redA0[4], redA1[4], redB0[4], redB1[4];
  int tid = threadIdx.x, b = blockIdx.x;
  int lane = tid & 63, w = tid >> 6;
  float mn = prm[2], s = prm[3];
  int r0 = 2 * b;
  const unsigned short* R0 = Mq + (long)r0 * NC;
  const unsigned short* R1 = R0 + NC;
  float lmu0 = logmu[r0], lmu1 = logmu[r0 + 1];
  float lnu[4];
#pragma unroll
  for (int cc = 0; cc < 4; ++cc) lnu[cc] = lognu[16 * b + w * 4 + cc];

  for (int it = 0; it < OT_ITERS; ++it){
    // ---- stage v (epoch it) into LDS: coalesced 8B pair loads + epoch poll ----
#pragma unroll
    for (int h = 0; h < 2; ++h){
      unsigned long long P[16];
#pragma unroll
      for (int q = 0; q < 16; ++q)
        P[q] = aload64(v2t + (h * 16 + q) * 256 + tid);
      for (;;){
        int bad = 0;
#pragma unroll
        for (int q = 0; q < 16; ++q)
          if ((unsigned)(P[q] >> 32) < (unsigned)it){
            bad = 1;
            P[q] = aload64(v2t + (h * 16 + q) * 256 + tid);
          }
        if (!bad) break;
        __builtin_amdgcn_s_sleep(1);
      }
#pragma unroll
      for (int q = 0; q < 16; ++q)
        sh[(h * 16 + q) * 256 + tid] = __uint_as_float((unsigned)P[q]);
    }
    __syncthreads();

    // ---- u-pass: rows r0, r0+1 (round-0-proven math, v from LDS) ----
    float t0[32], t1[32];
    float mx0 = -INFINITY, mx1 = -INFINITY;
#pragma unroll
    for (int kb = 0; kb < 4; ++kb){
      int cidx = kb * 2048 + tid * 8;
      uint4 qa = *(const uint4*)(R0 + cidx);
      uint4 qb = *(const uint4*)(R1 + cidx);
      float4 v0 = *(const float4*)(&sh[cidx]);
      float4 v1 = *(const float4*)(&sh[cidx + 4]);
      DQV8(t0, kb * 8, qa, v0, v1);
      DQV8(t1, kb * 8, qb, v0, v1);
#pragma unroll
      for (int q = 0; q < 8; ++q){
        mx0 = fmaxf(mx0, t0[kb * 8 + q]);
        mx1 = fmaxf(mx1, t1[kb * 8 + q]);
      }
    }
    float wm0 = wredMax(mx0), wm1 = wredMax(mx1);
    if (lane == 0){ redA0[w] = wm0; redA1[w] = wm1; }
    __syncthreads();
    float bm0 = fmaxf(fmaxf(redA0[0], redA0[1]), fmaxf(redA0[2], redA0[3]));
    float bm1 = fmaxf(fmaxf(redA1[0], redA1[1]), fmaxf(redA1[2], redA1[3]));
    float s0 = 0.f, s1 = 0.f;
#pragma unroll
    for (int q = 0; q < 32; ++q){ s0 += __expf(t0[q] - bm0); s1 += __expf(t1[q] - bm1); }
    s0 = wredSum(s0); s1 = wredSum(s1);
    if (lane == 0){ redB0[w] = s0; redB1[w] = s1; }
    __syncthreads();
    if (tid == 0){
      float nu0 = lmu0 - mn - (bm0 + __logf(redB0[0] + redB0[1] + redB0[2] + redB0[3]));
      float nu1 = lmu1 - mn - (bm1 + __logf(redB1[0] + redB1[1] + redB1[2] + redB1[3]));
      astore64(u2t + r0,     packVE(nu0, it + 1));
      astore64(u2t + r0 + 1, packVE(nu1, it + 1));
    }

    // ---- stage u (epoch it+1) into sh[0..1023]: pair loads + epoch poll ----
    // (sh v-region is dead past the redA sync; redA/redB are separate arrays)
    {
      unsigned long long PU[4];
#pragma unroll
      for (int q = 0; q < 4; ++q)
        PU[q] = aload64(u2t + q * 256 + tid);
      for (;;){
        int bad = 0;
#pragma unroll
        for (int q = 0; q < 4; ++q)
          if ((unsigned)(PU[q] >> 32) < (unsigned)(it + 1)){
            bad = 1;
            PU[q] = aload64(u2t + q * 256 + tid);
          }
        if (!bad) break;
        __builtin_amdgcn_s_sleep(1);
      }
#pragma unroll
      for (int q = 0; q < 4; ++q)
        sh[q * 256 + tid] = __uint_as_float((unsigned)PU[q]);
    }
    __syncthreads();

    // ---- v-pass: 16 cols per block, 4 per warp (round-0-proven math, u from LDS) ----
#pragma unroll
    for (int cc = 0; cc < 4; ++cc){
      int j = 16 * b + w * 4 + cc;
      const unsigned short* R = Mtq + (long)j * MR;
      uint4 qa = *(const uint4*)(R + lane * 8);
      uint4 qb = *(const uint4*)(R + 512 + lane * 8);
      float4 ua0 = *(const float4*)(&sh[lane * 8]);
      float4 ua1 = *(const float4*)(&sh[lane * 8 + 4]);
      float4 ub0 = *(const float4*)(&sh[512 + lane * 8]);
      float4 ub1 = *(const float4*)(&sh[512 + lane * 8 + 4]);
      float tv[16];
      DQV8(tv, 0, qa, ua0, ua1);
      DQV8(tv, 8, qb, ub0, ub1);
      float mx = -INFINITY;
#pragma unroll
      for (int q = 0; q < 16; ++q) mx = fmaxf(mx, tv[q]);
      mx = wredMax(mx);
      float sm = 0.f;
#pragma unroll
      for (int q = 0; q < 16; ++q) sm += __expf(tv[q] - mx);
      sm = wredSum(sm);
      if (lane == 0)
        astore64(v2t + j, packVE(lnu[cc] - mn - (mx + __logf(sm)), it + 1));
    }
    __syncthreads();   // protect sh before next iteration's v-stage overwrites it
  }
}

// fallback (host-serialized, no polling needed): used only if cooperative launch fails
__global__ __launch_bounds__(256) void kUPassQ(const unsigned short* __restrict__ Mq,
                                               const unsigned long long* __restrict__ v2t,
                                               const float* __restrict__ logmu,
                                               unsigned long long* __restrict__ u2t,
                                               const float* __restrict__ prm){
  int b = blockIdx.x, tid = threadIdx.x;
  float mn = prm[2], s = prm[3];
  int r0 = 2 * b;
  const unsigned short* R0 = Mq + (long)r0 * NC;
  const unsigned short* R1 = R0 + NC;
  const uint2* V2 = (const uint2*)v2t;
  float t0[32], t1[32];
  float mx0 = -INFINITY, mx1 = -INFINITY;
#pragma unroll
  for (int kb = 0; kb < 4; ++kb){
    int cidx = kb * 2048 + tid * 8;
    uint4 qa = *(const uint4*)(R0 + cidx);
    uint4 qb = *(const uint4*)(R1 + cidx);
    uint4 p0 = *(const uint4*)(V2 + cidx);
    uint4 p1 = *(const uint4*)(V2 + cidx + 2);
    uint4 p2 = *(const uint4*)(V2 + cidx + 4);
    uint4 p3 = *(const uint4*)(V2 + cidx + 6);
    float4 v0 = { __uint_as_float(p0.x), __uint_as_float(p0.z),
                  __uint_as_float(p1.x), __uint_as_float(p1.z) };
    float4 v1 = { __uint_as_float(p2.x), __uint_as_float(p2.z),
                  __uint_as_float(p3.x), __uint_as_float(p3.z) };
    DQV8(t0, kb * 8, qa, v0, v1);
    DQV8(t1, kb * 8, qb, v0, v1);
#pragma unroll
    for (int q = 0; q < 8; ++q){
      mx0 = fmaxf(mx0, t0[kb * 8 + q]);
      mx1 = fmaxf(mx1, t1[kb * 8 + q]);
    }
  }
  __shared__ float redA0[4], redA1[4], redB0[4], redB1[4];
  int lane = tid & 63, w = tid >> 6;
  float wm0 = wredMax(mx0), wm1 = wredMax(mx1);
  if (lane == 0){ redA0[w] = wm0; redA1[w] = wm1; }
  __syncthreads();
  float bm0 = fmaxf(fmaxf(redA0[0], redA0[1]), fmaxf(redA0[2], redA0[3]));
  float bm1 = fmaxf(fmaxf(redA1[0], redA1[1]), fmaxf(redA1[2], redA1[3]));
  float s0 = 0.f, s1 = 0.f;
#pragma unroll
  for (int q = 0; q < 32; ++q){ s0 += __expf(t0[q] - bm0); s1 += __expf(t1[q] - bm1); }
  s0 = wredSum(s0); s1 = wredSum(s1);
  if (lane == 0){ redB0[w] = s0; redB1[w] = s1; }
  __syncthreads();
  if (tid == 0){
    u2t[r0]     = packVE(logmu[r0]     - mn - (bm0 + __logf(redB0[0]+redB0[1]+redB0[2]+redB0[3])), 1);
    u2t[r0 + 1] = packVE(logmu[r0 + 1] - mn - (bm1 + __logf(redB1[0]+redB1[1]+redB1[2]+redB1[3])), 1);
  }
}

__global__ __launch_bounds__(256) void kVPassQ(const unsigned short* __restrict__ Mtq,
                                               const unsigned long long* __restrict__ u2t,
                                               const float* __restrict__ lognu,
                                               unsigned long long* __restrict__ v2t,
                                               const float* __restrict__ prm){
  __shared__ float ulds[1024];
  int tid = threadIdx.x;
  float mn = prm[2], s = prm[3];
  const uint2* U2 = (const uint2*)u2t;
  uint4 pu0 = *(const uint4*)(U2 + tid * 4);
  uint4 pu1 = *(const uint4*)(U2 + tid * 4 + 2);
  ulds[tid * 4 + 0] = __uint_as_float(pu0.x);
  ulds[tid * 4 + 1] = __uint_as_float(pu0.z);
  ulds[tid * 4 + 2] = __uint_as_float(pu1.x);
  ulds[tid * 4 + 3] = __uint_as_float(pu1.z);
  __syncthreads();
  int w = tid >> 6, lane = tid & 63;
#pragma unroll
  for (int cc = 0; cc < 4; ++cc){
    int j = blockIdx.x * 16 + w * 4 + cc;
    const unsigned short* R = Mtq + (long)j * MR;
    uint4 qa = *(const uint4*)(R + lane * 8);
    uint4 qb = *(const uint4*)(R + 512 + lane * 8);
    float4 ua0 = *(const float4*)(&ulds[lane * 8]);
    float4 ua1 = *(const float4*)(&ulds[lane * 8 + 4]);
    float4 ub0 = *(const float4*)(&ulds[512 + lane * 8]);
    float4 ub1 = *(const float4*)(&ulds[512 + lane * 8 + 4]);
    float tv[16];
    DQV8(tv, 0, qa, ua0, ua1);
    DQV8(tv, 8, qb, ub0, ub1);
    float mx = -INFINITY;
#pragma unroll
    for (int q = 0; q < 16; ++q) mx = fmaxf(mx, tv[q]);
    mx = wredMax(mx);
    float sm = 0.f;
#pragma unroll
    for (int q = 0; q < 16; ++q) sm += __expf(tv[q] - mx);
    sm = wredSum(sm);
    if (lane == 0) v2t[j] = packVE(lognu[j] - mn - (mx + __logf(sm)), 1);
  }
}

// K5: o = P@T rows, diff = mu*Q - o, acc += sum_i ||diff_i||_2 ; 4 rows per block
__global__ __launch_bounds__(256) void kFinal(const float* __restrict__ x,
                                              const float* __restrict__ att,
                                              const float* __restrict__ M,
                                              const unsigned long long* __restrict__ u2t,
                                              const unsigned long long* __restrict__ v2t,
                                              float* __restrict__ acc){
  __shared__ float pch[4][256];
  __shared__ float redS[4];
  int tid = threadIdx.x;
  int r0 = blockIdx.x * 4;
  const uint2* U2 = (const uint2*)u2t;
  const uint2* V2 = (const uint2*)v2t;
  float u4[4];
#pragma unroll
  for (int rr = 0; rr < 4; ++rr) u4[rr] = __uint_as_float(U2[r0 + rr].x);
  float o[4] = {0.f, 0.f, 0.f, 0.f};
  for (int jc = 0; jc < NC; jc += 256){
    float vv = __uint_as_float(V2[jc + tid].x);
#pragma unroll
    for (int rr = 0; rr < 4; ++rr)
      pch[rr][tid] = __expf(M[(long)(r0 + rr) * NC + jc + tid] + u4[rr] + vv);
    __syncthreads();
    int k = jc >> 10;
    const float* Tp = x + (1 + k) * IMG_STRIDE + tid * 1024 + (jc & 1023);
    for (int jj = 0; jj < 256; jj += 4){
      float4 tv = *(const float4*)(Tp + jj);
      float tq[4] = {tv.x, tv.y, tv.z, tv.w};
#pragma unroll
      for (int q = 0; q < 4; ++q){
        o[0] += pch[0][jj + q] * tq[q];
        o[1] += pch[1][jj + q] * tq[q];
        o[2] += pch[2][jj + q] * tq[q];
        o[3] += pch[3][jj + q] * tq[q];
      }
    }
    __syncthreads();
  }
  int lane = tid & 63, wid = tid >> 6;
  float dtot = 0.f;
#pragma unroll
  for (int rr = 0; rr < 4; ++rr){
    float mu = att[r0 + rr];
    float qv = x[tid * 1024 + (r0 + rr)];
    float diff = mu * qv - o[rr];
    float wsum = wredSum(diff * diff);
    if (lane == 0) redS[wid] = wsum;
    __syncthreads();
    if (tid == 0) dtot += sqrtf(redS[0] + redS[1] + redS[2] + redS[3]);
    __syncthreads();
  }
  if (tid == 0) atomicAdd(acc, dtot);
}

// K6: apply label/margin, write scalar output
__global__ void kOut(const float* __restrict__ acc, const int* __restrict__ label,
                     float* __restrict__ out){
  if (threadIdx.x == 0 && blockIdx.x == 0){
    float d = *acc;
    out[0] = (*label) ? d : fmaxf(0.7f - d, 0.f);
  }
}

extern "C" void kernel_launch(void* const* d_in, const int* in_sizes, int n_in,
                              void* d_out, int out_size, void* d_ws, size_t ws_size,
                              hipStream_t stream){
  const float* x   = (const float*)d_in[0];
  const float* att = (const float*)d_in[1];
  const int* label = (const int*)d_in[2];
  float* W = (float*)d_ws;
  float* out = (float*)d_out;

  float* M = W;                                                   // 32 MB
  unsigned short* Mq  = (unsigned short*)(W + 8388608);           // 16 MB
  unsigned short* Mtq = (unsigned short*)(W + 8388608 + 4194304); // 16 MB
  unsigned long long* u2t = (unsigned long long*)(W + 16777216);  // 1024 tagged u (8KB)
  unsigned long long* v2t = u2t + MR;                             // 8192 tagged v (64KB)
  float* S     = W + 16777216 + 2 * (MR + NC);                    // scalar area
  float* qq    = S;
  float* tt    = qq + 1024;
  float* logmu = tt + 8192;
  float* lognu = logmu + 1024;
  float* acc   = lognu + 8192;
  float* prm   = acc + 1;           // [0]=min key, [1]=max key, [2]=mn, [3]=scale
  unsigned* prmI = (unsigned*)prm;

  hipLaunchKernelGGL(kPrep, dim3(37), dim3(256), 0, stream, x, att, qq, tt, logmu, lognu, u2t, v2t, acc, prmI);
  hipLaunchKernelGGL(kGemmM, dim3(128, 16), dim3(256), 0, stream, x, qq, tt, M, prmI);
  hipLaunchKernelGGL(kQuantTrans, dim3(128, 16), dim3(256), 0, stream, M, Mq, Mtq, prm);

  void* args[] = { (void*)&Mq, (void*)&Mtq, (void*)&logmu, (void*)&lognu,
                   (void*)&u2t, (void*)&v2t, (void*)&prm };
  hipError_t rc = hipLaunchCooperativeKernel((const void*)kSink4,
                                             dim3(PBLK), dim3(256), args, 0, stream);
  if (rc != hipSuccess){
    for (int it = 0; it < OT_ITERS; ++it){
      hipLaunchKernelGGL(kUPassQ, dim3(512), dim3(256), 0, stream, Mq, v2t, logmu, u2t, prm);
      hipLaunchKernelGGL(kVPassQ, dim3(512), dim3(256), 0, stream, Mtq, u2t, lognu, v2t, prm);
    }
  }
  hipLaunchKernelGGL(kFinal, dim3(256), dim3(256), 0, stream, x, att, M, u2t, v2t, acc);
  hipLaunchKernelGGL(kOut, dim3(1), dim3(1), 0, stream, acc, label, out);
}

// Round 4
// 18306.888 us; speedup vs baseline: 1.0347x; 1.0347x over previous
//
#include <hip/hip_runtime.h>
#include <math.h>

// Problem constants (fixed by reference: x (9,256,32,32) fp32, att (9,32,32) fp32)
#define MR 1024      // m = 32*32 query locations
#define NC 8192      // n = 8*32*32 target locations
#define NCH 256      // channels
#define OT_ITERS 1000
#define IMG_STRIDE 262144  // 256*1024 floats per image
#define PBLK 512           // persistent grid: 2 blocks/CU (256-thread blocks)
#define LOG2E 1.4426950408889634f
#define TAU   1e-4f        // exit tolerance (~1-2 ulp at |u|~500)
#define NRTHR 4.0f         // warm->predictive switch threshold (exp2 headroom 127)

__device__ inline float wredMax(float v){
#pragma unroll
  for (int m = 32; m >= 1; m >>= 1) v = fmaxf(v, __shfl_xor(v, m, 64));
  return v;
}
__device__ inline float wredMin(float v){
#pragma unroll
  for (int m = 32; m >= 1; m >>= 1) v = fminf(v, __shfl_xor(v, m, 64));
  return v;
}
__device__ inline float wredSum(float v){
#pragma unroll
  for (int m = 32; m >= 1; m >>= 1) v += __shfl_xor(v, m, 64);
  return v;
}

// monotone float<->uint key (for atomicMin/Max over floats incl. negatives)
__device__ inline unsigned fkey(float f){
  unsigned b = __float_as_uint(f);
  return (b & 0x80000000u) ? ~b : (b | 0x80000000u);
}
__device__ inline float funkey(unsigned k){
  return (k & 0x80000000u) ? __uint_as_float(k & 0x7fffffffu) : __uint_as_float(~k);
}

// coherent (agent-scope) 4B load/store — R0-proven exchange mechanics
__device__ inline float aload(const float* p){
  return __hip_atomic_load(p, __ATOMIC_RELAXED, __HIP_MEMORY_SCOPE_AGENT);
}
__device__ inline void astore(float* p, float x){
  __hip_atomic_store(p, x, __ATOMIC_RELAXED, __HIP_MEMORY_SCOPE_AGENT);
}

// Mq column permutation: position of original column j within its row.
// u-pass thread t, batch kb, elem k handles original col j = kb*2048 + k*256 + t;
// stored at kb*2048 + t*8 + k so the thread's 8 elems are one uint4.
__device__ inline int PJ2(int j){ return (j & ~2047) | ((j & 255) << 3) | ((j >> 8) & 7); }
// Mtq row permutation: v-pass lane l, half H, elem k handles row i = H*512 + k*64 + l;
// stored at H*512 + l*8 + k.
__device__ inline int PI2(int i){ return (i & 512) | ((i & 63) << 3) | ((i >> 6) & 7); }

// unpack uint4 (8 u16) -> 8 floats (static indexing -> stays in VGPRs)
__device__ inline void upk8(uint4 q, float* f){
  f[0] = (float)(q.x & 0xFFFFu); f[1] = (float)(q.x >> 16);
  f[2] = (float)(q.y & 0xFFFFu); f[3] = (float)(q.y >> 16);
  f[4] = (float)(q.z & 0xFFFFu); f[5] = (float)(q.z >> 16);
  f[6] = (float)(q.w & 0xFFFFu); f[7] = (float)(q.w >> 16);
}

// K1: squared norms, log marginals, zero-init u,v,acc, minmax keys, barrier state
__global__ __launch_bounds__(256) void kPrep(const float* __restrict__ x,
                                             const float* __restrict__ att,
                                             float* __restrict__ qq, float* __restrict__ tt,
                                             float* __restrict__ logmu, float* __restrict__ lognu,
                                             float* __restrict__ u, float* __restrict__ v,
                                             float* __restrict__ acc, unsigned* __restrict__ prmI,
                                             int* __restrict__ bar){
  int idx = blockIdx.x * 256 + threadIdx.x;
  if (idx < 9216){
    int img = idx >> 10, pos = idx & 1023;
    const float* p = x + img * IMG_STRIDE + pos;
    float s = 0.f;
#pragma unroll 8
    for (int c = 0; c < NCH; ++c){ float a = p[c * 1024]; s += a * a; }
    float lg = logf(att[idx]);
    if (img == 0){ qq[idx] = s;        logmu[idx] = lg; }
    else         { tt[idx - 1024] = s; lognu[idx - 1024] = lg; }
  }
  if (idx < MR) u[idx] = 0.f;
  if (idx < NC) v[idx] = 0.f;
  if (idx < 1024) bar[idx] = 0;
  if (idx == 0){ *acc = 0.f; prmI[0] = 0xFFFFFFFFu; prmI[1] = 0u; }
}

// K2: M[i][j] = qq[i] + tt[j] - 2 * Q_i . T_j ; also global min/max via key atomics
__global__ __launch_bounds__(256) void kGemmM(const float* __restrict__ x,
                                              const float* __restrict__ qq,
                                              const float* __restrict__ tt,
                                              float* __restrict__ M,
                                              unsigned* __restrict__ prmI){
  __shared__ float As[16][68];
  __shared__ float Bs[16][68];
  __shared__ float smn[4], smx[4];
  int jb = blockIdx.x;
  int ib = blockIdx.y;
  int i0 = ib * 64;
  int j0 = jb * 64;
  int k  = j0 >> 10, p0 = j0 & 1023;
  const float* A = x + i0;
  const float* B = x + (1 + k) * IMG_STRIDE + p0;
  int tid = threadIdx.x;
  int lr = tid >> 4, lc = (tid & 15) * 4;
  int ty = tid >> 4, tx = tid & 15;
  float accv[4][4] = {};
  for (int kt = 0; kt < 16; ++kt){
    int c = kt * 16 + lr;
    float4 av = *(const float4*)(A + c * 1024 + lc);
    float4 bv = *(const float4*)(B + c * 1024 + lc);
    *(float4*)(&As[lr][lc]) = av;
    *(float4*)(&Bs[lr][lc]) = bv;
    __syncthreads();
#pragma unroll
    for (int kk = 0; kk < 16; ++kk){
      float4 a = *(const float4*)(&As[kk][ty * 4]);
      float4 b = *(const float4*)(&Bs[kk][tx * 4]);
      float ar[4] = {a.x, a.y, a.z, a.w};
      float br[4] = {b.x, b.y, b.z, b.w};
#pragma unroll
      for (int r = 0; r < 4; ++r)
#pragma unroll
        for (int cc = 0; cc < 4; ++cc) accv[r][cc] += ar[r] * br[cc];
    }
    __syncthreads();
  }
  float tmn = INFINITY, tmx = -INFINITY;
#pragma unroll
  for (int r = 0; r < 4; ++r){
    int i = i0 + ty * 4 + r;
    float qi = qq[i];
    float o[4];
#pragma unroll
    for (int cc = 0; cc < 4; ++cc){
      o[cc] = qi + tt[j0 + tx * 4 + cc] - 2.f * accv[r][cc];
      tmn = fminf(tmn, o[cc]); tmx = fmaxf(tmx, o[cc]);
    }
    float4 ov = { o[0], o[1], o[2], o[3] };
    *(float4*)(M + (long)i * NC + j0 + tx * 4) = ov;
  }
  int lane = tid & 63, w = tid >> 6;
  tmn = wredMin(tmn); tmx = wredMax(tmx);
  if (lane == 0){ smn[w] = tmn; smx[w] = tmx; }
  __syncthreads();
  if (tid == 0){
    float bmn = fminf(fminf(smn[0], smn[1]), fminf(smn[2], smn[3]));
    float bmx = fmaxf(fmaxf(smx[0], smx[1]), fmaxf(smx[2], smx[3]));
    atomicMin(&prmI[0], fkey(bmn));
    atomicMax(&prmI[1], fkey(bmx));
  }
}

// K2b: one pass over M -> Mq (u16, PERMUTED cols) + Mtq (u16 transposed, PERMUTED rows)
__global__ __launch_bounds__(256) void kQuantTrans(const float* __restrict__ M,
                                                   unsigned short* __restrict__ Mq,
                                                   unsigned short* __restrict__ Mtq,
                                                   float* __restrict__ prm){
  __shared__ float tile[64][65];
  const unsigned* prmI = (const unsigned*)prm;
  float mn = funkey(prmI[0]);
  float mx = funkey(prmI[1]);
  float rng = mx - mn;
  float inv = (rng > 0.f) ? 65535.0f / rng : 0.f;
  float sc  = (rng > 0.f) ? rng / 65535.0f : 0.f;
  int i0 = blockIdx.y * 64;
  int j0 = blockIdx.x * 64;
  int t = threadIdx.x;
  int tc = t & 63, tr = t >> 6;
#pragma unroll
  for (int rr = 0; rr < 64; rr += 4)
    tile[rr + tr][tc] = M[(long)(i0 + rr + tr) * NC + j0 + tc];
  __syncthreads();
#pragma unroll
  for (int rr = 0; rr < 64; rr += 4){
    float a = tile[rr + tr][tc];
    int qa = (int)lrintf((a - mn) * inv);
    qa = qa < 0 ? 0 : (qa > 65535 ? 65535 : qa);
    Mq[(long)(i0 + rr + tr) * NC + PJ2(j0 + tc)] = (unsigned short)qa;
    float b = tile[tc][rr + tr];
    int qb = (int)lrintf((b - mn) * inv);
    qb = qb < 0 ? 0 : (qb > 65535 ? 65535 : qb);
    Mtq[(long)(j0 + rr + tr) * MR + PI2(i0 + tc)] = (unsigned short)qb;
  }
  if (blockIdx.x == 0 && blockIdx.y == 0 && t == 0){ prm[2] = mn; prm[3] = sc; }
}

// hierarchical epoch grid barrier: 8 groups of 64 blocks; relaxed atomics only
__device__ inline void gbar(int* bar, int g, int ep){
  __syncthreads();
  if (threadIdx.x == 0){
    asm volatile("s_waitcnt vmcnt(0)" ::: "memory");  // prior agent-stores complete
    int a = __hip_atomic_fetch_add(&bar[g * 32], 1, __ATOMIC_RELAXED, __HIP_MEMORY_SCOPE_AGENT);
    if (a == 64 * ep - 1){                            // last arrival of this group
      int go = __hip_atomic_fetch_add(&bar[512], 1, __ATOMIC_RELAXED, __HIP_MEMORY_SCOPE_AGENT);
      if (go == 8 * ep - 1){                          // last group: publish release epoch
#pragma unroll
        for (int g2 = 0; g2 < 8; ++g2)
          __hip_atomic_store(&bar[256 + g2 * 32], ep, __ATOMIC_RELAXED, __HIP_MEMORY_SCOPE_AGENT);
      }
    }
    while (__hip_atomic_load(&bar[256 + g * 32], __ATOMIC_RELAXED, __HIP_MEMORY_SCOPE_AGENT) < ep)
      __builtin_amdgcn_s_sleep(4);
  }
  __syncthreads();
}

// persistent Sinkhorn, R0 skeleton (512x256, 2 gbar/iter) with:
//  (a) permuted Mq/Mtq -> ALL u/v operand loads directly coalesced, zero LDS staging
//  (b) predictive normalizer after warm-up: c = prev lse (exact for any c), single
//      fused exp2 pass, no max reduction;  u_new = u_prev - ln(S)
//  (c) ulp-level early exit when all |du|,|dv| < TAU in one iteration (global flag)
__global__ __launch_bounds__(256, 2) void kSink5(const unsigned short* __restrict__ Mq,
                                                 const unsigned short* __restrict__ Mtq,
                                                 const float* __restrict__ logmu,
                                                 const float* __restrict__ lognu,
                                                 float* __restrict__ u,
                                                 float* __restrict__ v,
                                                 const float* __restrict__ prm,
                                                 int* __restrict__ bar){
  __shared__ float redA0[4], redA1[4], redB0[4], redB1[4];
  __shared__ int sChg, sNR, sCtl;
  int tid = threadIdx.x, b = blockIdx.x;
  int lane = tid & 63, w = tid >> 6, g = b & 7;
  float mn = prm[2], s = prm[3];
  float s2 = s * LOG2E;
  int r0 = 2 * b;
  const unsigned short* R0p = Mq + (long)r0 * NC + tid * 8;
  const unsigned short* R1p = R0p + NC;
  float lmu0 = logmu[r0], lmu1 = logmu[r0 + 1];
  float lnu[4];
#pragma unroll
  for (int cc = 0; cc < 4; ++cc) lnu[cc] = lognu[16 * b + w * 4 + cc];
  float prevU0 = 0.f, prevU1 = 0.f;
  float prevV[4] = {0.f, 0.f, 0.f, 0.f};
  int pred = 0, ep = 0;
  if (tid == 0){ sChg = 0; sNR = 0; sCtl = 0; }
  __syncthreads();

  for (int it = 0; it < OT_ITERS; ++it){
    // ---- u-pass operands: 32 coalesced coherent v-loads + 8 uint4 Mq loads ----
    float vr[32];
#pragma unroll
    for (int kb = 0; kb < 4; ++kb)
#pragma unroll
      for (int k = 0; k < 8; ++k)
        vr[kb * 8 + k] = aload(v + kb * 2048 + k * 256 + tid);
    uint4 qa[4], qb[4];
#pragma unroll
    for (int kb = 0; kb < 4; ++kb){
      qa[kb] = *(const uint4*)(R0p + kb * 2048);
      qb[kb] = *(const uint4*)(R1p + kb * 2048);
    }
    float du0, du1, nu0, nu1;
    if (!pred){
      // warm: exact max-based two-pass (recompute t in 2nd pass; no t[] arrays)
      float mx0 = -INFINITY, mx1 = -INFINITY;
#pragma unroll
      for (int kb = 0; kb < 4; ++kb){
        float f0[8], f1[8];
        upk8(qa[kb], f0); upk8(qb[kb], f1);
#pragma unroll
        for (int k = 0; k < 8; ++k){
          mx0 = fmaxf(mx0, fmaf(s, f0[k], vr[kb * 8 + k]));
          mx1 = fmaxf(mx1, fmaf(s, f1[k], vr[kb * 8 + k]));
        }
      }
      float wm0 = wredMax(mx0), wm1 = wredMax(mx1);
      if (lane == 0){ redA0[w] = wm0; redA1[w] = wm1; }
      __syncthreads();
      float bm0 = fmaxf(fmaxf(redA0[0], redA0[1]), fmaxf(redA0[2], redA0[3]));
      float bm1 = fmaxf(fmaxf(redA1[0], redA1[1]), fmaxf(redA1[2], redA1[3]));
      float e0 = 0.f, e1 = 0.f;
#pragma unroll
      for (int kb = 0; kb < 4; ++kb){
        float f0[8], f1[8];
        upk8(qa[kb], f0); upk8(qb[kb], f1);
#pragma unroll
        for (int k = 0; k < 8; ++k){
          e0 += __expf(fmaf(s, f0[k], vr[kb * 8 + k]) - bm0);
          e1 += __expf(fmaf(s, f1[k], vr[kb * 8 + k]) - bm1);
        }
      }
      e0 = wredSum(e0); e1 = wredSum(e1);
      if (lane == 0){ redB0[w] = e0; redB1[w] = e1; }
      __syncthreads();
      float St0 = (redB0[0] + redB0[1]) + (redB0[2] + redB0[3]);
      float St1 = (redB1[0] + redB1[1]) + (redB1[2] + redB1[3]);
      nu0 = lmu0 - mn - (bm0 + __logf(St0));
      nu1 = lmu1 - mn - (bm1 + __logf(St1));
      du0 = nu0 - prevU0; du1 = nu1 - prevU1;
    } else {
      // predictive: c = previous lse; exact log-domain update u_new = u_prev - ln S
      float cl0 = (lmu0 - mn - prevU0) * LOG2E;
      float cl1 = (lmu1 - mn - prevU1) * LOG2E;
      float S0 = 0.f, S1 = 0.f;
#pragma unroll
      for (int kb = 0; kb < 4; ++kb){
        float f0[8], f1[8];
        upk8(qa[kb], f0); upk8(qb[kb], f1);
#pragma unroll
        for (int k = 0; k < 8; ++k){
          float vl = vr[kb * 8 + k] * LOG2E;
          S0 += exp2f(fmaf(s2, f0[k], vl - cl0));
          S1 += exp2f(fmaf(s2, f1[k], vl - cl1));
        }
      }
      S0 = wredSum(S0); S1 = wredSum(S1);
      if (lane == 0){ redB0[w] = S0; redB1[w] = S1; }
      __syncthreads();
      float St0 = (redB0[0] + redB0[1]) + (redB0[2] + redB0[3]);
      float St1 = (redB1[0] + redB1[1]) + (redB1[2] + redB1[3]);
      du0 = -__logf(St0); du1 = -__logf(St1);
      nu0 = prevU0 + du0; nu1 = prevU1 + du1;
    }
    prevU0 = nu0; prevU1 = nu1;
    if (tid == 0){ astore(u + r0, nu0); astore(u + r0 + 1, nu1); }
    gbar(bar, g, ++ep);   // u complete everywhere

    // ---- v-pass: 16 coalesced coherent u-loads (shared across 4 cols/warp) ----
    float ur[16];
#pragma unroll
    for (int H = 0; H < 2; ++H)
#pragma unroll
      for (int k = 0; k < 8; ++k)
        ur[H * 8 + k] = aload(u + H * 512 + k * 64 + lane);
    int wchg = 0, wnr = 0;
#pragma unroll
    for (int cc = 0; cc < 4; ++cc){
      int j = 16 * b + w * 4 + cc;
      const unsigned short* R = Mtq + (long)j * MR + lane * 8;
      uint4 ca = *(const uint4*)(R);
      uint4 cb = *(const uint4*)(R + 512);
      float qf[16];
      upk8(ca, qf); upk8(cb, qf + 8);
      float dv, nv;
      if (!pred){
        float tv[16];
#pragma unroll
        for (int q = 0; q < 16; ++q) tv[q] = fmaf(s, qf[q], ur[q]);
        float mx = -INFINITY;
#pragma unroll
        for (int q = 0; q < 16; ++q) mx = fmaxf(mx, tv[q]);
        mx = wredMax(mx);
        float sm = 0.f;
#pragma unroll
        for (int q = 0; q < 16; ++q) sm += __expf(tv[q] - mx);
        sm = wredSum(sm);
        nv = lnu[cc] - mn - (mx + __logf(sm));
        dv = nv - prevV[cc];
      } else {
        float cl = (lnu[cc] - mn - prevV[cc]) * LOG2E;
        float S = 0.f;
#pragma unroll
        for (int q = 0; q < 16; ++q)
          S += exp2f(fmaf(s2, qf[q], ur[q] * LOG2E - cl));
        S = wredSum(S);
        dv = -__logf(S);
        nv = prevV[cc] + dv;
      }
      prevV[cc] = nv;
      if (fabsf(dv) > TAU)   wchg = 1;
      if (fabsf(dv) > NRTHR) wnr = 1;
      if (lane == 0) astore(v + j, nv);
    }
    int uchg = (fabsf(du0) > TAU)   || (fabsf(du1) > TAU);
    int unr  = (fabsf(du0) > NRTHR) || (fabsf(du1) > NRTHR);
    if (lane == 0){ if (wchg) sChg = 1; if (wnr) sNR = 1; }
    asm volatile("s_waitcnt vmcnt(0)" ::: "memory");  // drain v-stores of ALL warps
    __syncthreads();
    if (tid == 0){
      if (uchg || sChg)
        __hip_atomic_fetch_max(&bar[768], it + 1, __ATOMIC_RELAXED, __HIP_MEMORY_SCOPE_AGENT);
      if (unr || sNR)
        __hip_atomic_fetch_max(&bar[769], it + 1, __ATOMIC_RELAXED, __HIP_MEMORY_SCOPE_AGENT);
    }
    gbar(bar, g, ++ep);   // v complete everywhere; flags visible

    if (tid == 0){
      int lc  = __hip_atomic_load(&bar[768], __ATOMIC_RELAXED, __HIP_MEMORY_SCOPE_AGENT);
      int lnr = __hip_atomic_load(&bar[769], __ATOMIC_RELAXED, __HIP_MEMORY_SCOPE_AGENT);
      sCtl = ((pred && lc < it + 1) ? 1 : 0) | ((lnr < it + 1) ? 2 : 0);
      sChg = 0; sNR = 0;
    }
    __syncthreads();
    int ctl = sCtl;
    if (ctl & 1) break;      // fixed point everywhere -> exact early exit
    pred = (ctl >> 1) & 1;   // global, consistent warm->predictive switch
  }
}

// fallback (host-serialized): max-based, permuted layouts, full 1000 iters
__global__ __launch_bounds__(256) void kUPassQ(const unsigned short* __restrict__ Mq,
                                               const float* __restrict__ v,
                                               const float* __restrict__ logmu,
                                               float* __restrict__ u,
                                               const float* __restrict__ prm){
  __shared__ float redA0[4], redA1[4], redB0[4], redB1[4];
  int b = blockIdx.x, tid = threadIdx.x;
  int lane = tid & 63, w = tid >> 6;
  float mn = prm[2], s = prm[3];
  int r0 = 2 * b;
  const unsigned short* R0p = Mq + (long)r0 * NC + tid * 8;
  const unsigned short* R1p = R0p + NC;
  float vr[32];
#pragma unroll
  for (int kb = 0; kb < 4; ++kb)
#pragma unroll
    for (int k = 0; k < 8; ++k)
      vr[kb * 8 + k] = v[kb * 2048 + k * 256 + tid];
  uint4 qa[4], qb[4];
#pragma unroll
  for (int kb = 0; kb < 4; ++kb){
    qa[kb] = *(const uint4*)(R0p + kb * 2048);
    qb[kb] = *(const uint4*)(R1p + kb * 2048);
  }
  float mx0 = -INFINITY, mx1 = -INFINITY;
#pragma unroll
  for (int kb = 0; kb < 4; ++kb){
    float f0[8], f1[8];
    upk8(qa[kb], f0); upk8(qb[kb], f1);
#pragma unroll
    for (int k = 0; k < 8; ++k){
      mx0 = fmaxf(mx0, fmaf(s, f0[k], vr[kb * 8 + k]));
      mx1 = fmaxf(mx1, fmaf(s, f1[k], vr[kb * 8 + k]));
    }
  }
  float wm0 = wredMax(mx0), wm1 = wredMax(mx1);
  if (lane == 0){ redA0[w] = wm0; redA1[w] = wm1; }
  __syncthreads();
  float bm0 = fmaxf(fmaxf(redA0[0], redA0[1]), fmaxf(redA0[2], redA0[3]));
  float bm1 = fmaxf(fmaxf(redA1[0], redA1[1]), fmaxf(redA1[2], redA1[3]));
  float e0 = 0.f, e1 = 0.f;
#pragma unroll
  for (int kb = 0; kb < 4; ++kb){
    float f0[8], f1[8];
    upk8(qa[kb], f0); upk8(qb[kb], f1);
#pragma unroll
    for (int k = 0; k < 8; ++k){
      e0 += __expf(fmaf(s, f0[k], vr[kb * 8 + k]) - bm0);
      e1 += __expf(fmaf(s, f1[k], vr[kb * 8 + k]) - bm1);
    }
  }
  e0 = wredSum(e0); e1 = wredSum(e1);
  if (lane == 0){ redB0[w] = e0; redB1[w] = e1; }
  __syncthreads();
  if (tid == 0){
    u[r0]     = logmu[r0]     - mn - (bm0 + __logf(redB0[0] + redB0[1] + redB0[2] + redB0[3]));
    u[r0 + 1] = logmu[r0 + 1] - mn - (bm1 + __logf(redB1[0] + redB1[1] + redB1[2] + redB1[3]));
  }
}

__global__ __launch_bounds__(256) void kVPassQ(const unsigned short* __restrict__ Mtq,
                                               const float* __restrict__ u,
                                               const float* __restrict__ lognu,
                                               float* __restrict__ v,
                                               const float* __restrict__ prm){
  int tid = threadIdx.x;
  int w = tid >> 6, lane = tid & 63;
  float mn = prm[2], s = prm[3];
  float ur[16];
#pragma unroll
  for (int H = 0; H < 2; ++H)
#pragma unroll
    for (int k = 0; k < 8; ++k)
      ur[H * 8 + k] = u[H * 512 + k * 64 + lane];
#pragma unroll
  for (int cc = 0; cc < 4; ++cc){
    int j = blockIdx.x * 16 + w * 4 + cc;
    const unsigned short* R = Mtq + (long)j * MR + lane * 8;
    uint4 ca = *(const uint4*)(R);
    uint4 cb = *(const uint4*)(R + 512);
    float qf[16];
    upk8(ca, qf); upk8(cb, qf + 8);
    float tv[16];
#pragma unroll
    for (int q = 0; q < 16; ++q) tv[q] = fmaf(s, qf[q], ur[q]);
    float mx = -INFINITY;
#pragma unroll
    for (int q = 0; q < 16; ++q) mx = fmaxf(mx, tv[q]);
    mx = wredMax(mx);
    float sm = 0.f;
#pragma unroll
    for (int q = 0; q < 16; ++q) sm += __expf(tv[q] - mx);
    sm = wredSum(sm);
    if (lane == 0) v[j] = lognu[j] - mn - (mx + __logf(sm));
  }
}

// K5: o = P@T rows, diff = mu*Q - o, acc += sum_i ||diff_i||_2 ; 4 rows per block
__global__ __launch_bounds__(256) void kFinal(const float* __restrict__ x,
                                              const float* __restrict__ att,
                                              const float* __restrict__ M,
                                              const float* __restrict__ u,
                                              const float* __restrict__ v,
                                              float* __restrict__ acc){
  __shared__ float pch[4][256];
  __shared__ float redS[4];
  int tid = threadIdx.x;
  int r0 = blockIdx.x * 4;
  float u4[4];
#pragma unroll
  for (int rr = 0; rr < 4; ++rr) u4[rr] = u[r0 + rr];
  float o[4] = {0.f, 0.f, 0.f, 0.f};
  for (int jc = 0; jc < NC; jc += 256){
    float vv = v[jc + tid];
#pragma unroll
    for (int rr = 0; rr < 4; ++rr)
      pch[rr][tid] = __expf(M[(long)(r0 + rr) * NC + jc + tid] + u4[rr] + vv);
    __syncthreads();
    int k = jc >> 10;
    const float* Tp = x + (1 + k) * IMG_STRIDE + tid * 1024 + (jc & 1023);
    for (int jj = 0; jj < 256; jj += 4){
      float4 tv = *(const float4*)(Tp + jj);
      float tq[4] = {tv.x, tv.y, tv.z, tv.w};
#pragma unroll
      for (int q = 0; q < 4; ++q){
        o[0] += pch[0][jj + q] * tq[q];
        o[1] += pch[1][jj + q] * tq[q];
        o[2] += pch[2][jj + q] * tq[q];
        o[3] += pch[3][jj + q] * tq[q];
      }
    }
    __syncthreads();
  }
  int lane = tid & 63, wid = tid >> 6;
  float dtot = 0.f;
#pragma unroll
  for (int rr = 0; rr < 4; ++rr){
    float mu = att[r0 + rr];
    float qv = x[tid * 1024 + (r0 + rr)];
    float diff = mu * qv - o[rr];
    float wsum = wredSum(diff * diff);
    if (lane == 0) redS[wid] = wsum;
    __syncthreads();
    if (tid == 0) dtot += sqrtf(redS[0] + redS[1] + redS[2] + redS[3]);
    __syncthreads();
  }
  if (tid == 0) atomicAdd(acc, dtot);
}

// K6: apply label/margin, write scalar output
__global__ void kOut(const float* __restrict__ acc, const int* __restrict__ label,
                     float* __restrict__ out){
  if (threadIdx.x == 0 && blockIdx.x == 0){
    float d = *acc;
    out[0] = (*label) ? d : fmaxf(0.7f - d, 0.f);
  }
}

extern "C" void kernel_launch(void* const* d_in, const int* in_sizes, int n_in,
                              void* d_out, int out_size, void* d_ws, size_t ws_size,
                              hipStream_t stream){
  const float* x   = (const float*)d_in[0];
  const float* att = (const float*)d_in[1];
  const int* label = (const int*)d_in[2];
  float* W = (float*)d_ws;
  float* out = (float*)d_out;

  float* M = W;                                                   // 32 MB
  unsigned short* Mq  = (unsigned short*)(W + 8388608);           // 16 MB
  unsigned short* Mtq = (unsigned short*)(W + 8388608 + 4194304); // 16 MB
  float* S     = W + 16777216;
  float* qq    = S;
  float* tt    = qq + 1024;
  float* logmu = tt + 8192;
  float* lognu = logmu + 1024;
  float* u     = lognu + 8192;
  float* v     = u + 1024;
  float* acc   = v + 8192;
  float* prm   = acc + 1;           // [0]=min key, [1]=max key, [2]=mn, [3]=scale
  unsigned* prmI = (unsigned*)prm;
  int*   bar   = (int*)(prm + 4);   // 1024 ints: barrier state + flags @768/769

  hipLaunchKernelGGL(kPrep, dim3(37), dim3(256), 0, stream, x, att, qq, tt, logmu, lognu, u, v, acc, prmI, bar);
  hipLaunchKernelGGL(kGemmM, dim3(128, 16), dim3(256), 0, stream, x, qq, tt, M, prmI);
  hipLaunchKernelGGL(kQuantTrans, dim3(128, 16), dim3(256), 0, stream, M, Mq, Mtq, prm);

  void* args[] = { (void*)&Mq, (void*)&Mtq, (void*)&logmu, (void*)&lognu,
                   (void*)&u, (void*)&v, (void*)&prm, (void*)&bar };
  hipError_t rc = hipLaunchCooperativeKernel((const void*)kSink5,
                                             dim3(PBLK), dim3(256), args, 0, stream);
  if (rc != hipSuccess){
    for (int it = 0; it < OT_ITERS; ++it){
      hipLaunchKernelGGL(kUPassQ, dim3(512), dim3(256), 0, stream, Mq, v, logmu, u, prm);
      hipLaunchKernelGGL(kVPassQ, dim3(512), dim3(256), 0, stream, Mtq, u, lognu, v, prm);
    }
  }
  hipLaunchKernelGGL(kFinal, dim3(256), dim3(256), 0, stream, x, att, M, u, v, acc);
  hipLaunchKernelGGL(kOut, dim3(1), dim3(1), 0, stream, acc, label, out);
}